// Round 1
// baseline (240.357 us; speedup 1.0000x reference)
//
#include <hip/hip_runtime.h>
#include <hip/hip_bf16.h>
#include <stdint.h>

typedef unsigned short u16;
typedef __attribute__((ext_vector_type(8))) __bf16 bf16x8;
typedef __attribute__((ext_vector_type(4))) float f32x4;
typedef __attribute__((ext_vector_type(8))) u16 u16x8;

__device__ __forceinline__ u16 f2bf(float f) {
  union { float f; unsigned int u; } v; v.f = f;
  unsigned int r = v.u + 0x7fffu + ((v.u >> 16) & 1u);
  return (u16)(r >> 16);
}

__device__ __forceinline__ f32x4 mfma16(bf16x8 a, bf16x8 b, f32x4 c) {
  return __builtin_amdgcn_mfma_f32_16x16x32_bf16(a, b, c, 0, 0, 0);
}

__device__ __forceinline__ void gload16(const void* g, void* l) {
  __builtin_amdgcn_global_load_lds((const __attribute__((address_space(1))) void*)g,
                                   (__attribute__((address_space(3))) void*)l,
                                   16, 0, 0);
}

// ---------------- elementwise cast fp32 -> bf16 ----------------
__global__ void cast_bf16_kernel(const float* __restrict__ in, u16* __restrict__ out, int n) {
  int i = (blockIdx.x * 256 + threadIdx.x) * 8;
  if (i >= n) return;
  const float4* p = (const float4*)(in + i);
  float4 a = p[0], b = p[1];
  u16x8 o;
  o[0] = f2bf(a.x); o[1] = f2bf(a.y); o[2] = f2bf(a.z); o[3] = f2bf(a.w);
  o[4] = f2bf(b.x); o[5] = f2bf(b.y); o[6] = f2bf(b.z); o[7] = f2bf(b.w);
  *(u16x8*)(out + i) = o;
}

// ---------------- transpose + cast: in[R][C] fp32 -> out[C][R] bf16 ----------------
__global__ void transpose_cast_k(const float* __restrict__ in, u16* __restrict__ out,
                                 int R, int Ccols) {
  __shared__ float tile[64][65];
  const int c0 = (int)blockIdx.x << 6, r0 = (int)blockIdx.y << 6;
  const int tx = threadIdx.x & 63, ty = threadIdx.x >> 6;
#pragma unroll
  for (int i = ty; i < 64; i += 4)
    tile[i][tx] = in[(size_t)(r0 + i) * Ccols + c0 + tx];
  __syncthreads();
#pragma unroll
  for (int i = ty; i < 64; i += 4)
    out[(size_t)(c0 + i) * R + r0 + tx] = f2bf(tile[tx][i]);
}

// ---------------- GEMM: C[M][N] = A_bf16[M][K] @ Bt_bf16[N][K]^T + bias ----------------
// 128x128 tile, BK=32, 256 threads (4 waves in 2x2), 16x16x32 bf16 MFMA.
__global__ __launch_bounds__(256, 2)
void gemm_bt(const u16* __restrict__ A, const u16* __restrict__ Bt,
             const float* __restrict__ bias, float* __restrict__ C,
             int M, int N, int K) {
  __shared__ u16 As[128 * 32];
  __shared__ u16 Bs[128 * 32];
  const int nb = N >> 7;
  const int m0 = (int)(blockIdx.x / nb) << 7;
  const int n0 = (int)(blockIdx.x % nb) << 7;
  const int tid = threadIdx.x;
  const int l = tid & 63, lg = l >> 4, ll = l & 15;
  const int w = tid >> 6;
  const int wr = (w >> 1) << 6, wc = (w & 1) << 6;
  const int srow = tid >> 2, scol = (tid & 3) << 3;
  const u16* ga = A + (size_t)(m0 + srow) * K + scol;
  const u16* gb = Bt + (size_t)(n0 + srow) * K + scol;
  u16* la0 = &As[srow * 32 + scol];
  u16* la1 = &As[(srow + 64) * 32 + scol];
  u16* lb0 = &Bs[srow * 32 + scol];
  u16* lb1 = &Bs[(srow + 64) * 32 + scol];
  const size_t K64 = (size_t)64 * K;
  f32x4 acc[4][4] = {};
  for (int kt = 0; kt < K; kt += 32) {
    gload16(ga + kt, la0);
    gload16(ga + kt + K64, la1);
    gload16(gb + kt, lb0);
    gload16(gb + kt + K64, lb1);
    __syncthreads();  // drains vmcnt + barrier
    bf16x8 a[4], b[4];
#pragma unroll
    for (int i = 0; i < 4; ++i) {
      a[i] = *(const bf16x8*)&As[(wr + i * 16 + ll) * 32 + lg * 8];
      b[i] = *(const bf16x8*)&Bs[(wc + i * 16 + ll) * 32 + lg * 8];
    }
#pragma unroll
    for (int mi = 0; mi < 4; ++mi)
#pragma unroll
      for (int ni = 0; ni < 4; ++ni)
        acc[mi][ni] = mfma16(a[mi], b[ni], acc[mi][ni]);
    __syncthreads();
  }
  // epilogue: C/D layout col=lane&15, row=(lane>>4)*4+reg (verified m89/m91)
#pragma unroll
  for (int mi = 0; mi < 4; ++mi) {
#pragma unroll
    for (int r = 0; r < 4; ++r) {
      const int row = m0 + wr + mi * 16 + lg * 4 + r;
      float* crow = C + (size_t)row * N + n0 + wc;
#pragma unroll
      for (int ni = 0; ni < 4; ++ni)
        crow[ni * 16 + ll] = acc[mi][ni][r] + bias[n0 + wc + ni * 16 + ll];
    }
  }
}

// ---------------- RoPE on q,k; split to head-major bf16; scale folded into q ----------------
__global__ void rope_split_k(const float* __restrict__ qkv,
                             const float* __restrict__ fc, const float* __restrict__ fs,
                             u16* __restrict__ qr, u16* __restrict__ kr) {
  const int t = blockIdx.x;            // token 0..4095
  const int b = t >> 11, s = t & 2047;
  const int h = threadIdx.x >> 5, i = threadIdx.x & 31;
  const float c = fc[s * 32 + i], sn = fs[s * 32 + i];
  const float* qp = qkv + (size_t)t * 3072 + (h << 6) + 2 * i;
  const float qe = qp[0], qo = qp[1];
  const float ke = qp[1024], ko = qp[1025];
  const size_t ob = (((size_t)((b << 4) + h) << 11) + s) * 64 + 2 * i;
  qr[ob]     = f2bf((qe * c - qo * sn) * 0.125f);
  qr[ob + 1] = f2bf((qe * sn + qo * c) * 0.125f);
  kr[ob]     = f2bf(ke * c - ko * sn);
  kr[ob + 1] = f2bf(ke * sn + ko * c);
}

// ---------------- V: qkv fp32 token-major -> vt[bh][d][s] bf16 (transposed) ----------------
__global__ void v_transpose_k(const float* __restrict__ qkv, u16* __restrict__ vt) {
  __shared__ float tile[64][65];
  const int bh = blockIdx.x;
  const int b = bh >> 4, h = bh & 15;
  const int s0 = (int)blockIdx.y << 6;
  const int tx = threadIdx.x & 63, ty = threadIdx.x >> 6;
#pragma unroll
  for (int i = ty; i < 64; i += 4)
    tile[i][tx] = qkv[(size_t)((b << 11) + s0 + i) * 3072 + 2048 + (h << 6) + tx];
  __syncthreads();
#pragma unroll
  for (int i = ty; i < 64; i += 4)
    vt[((size_t)(bh << 6) + i) * 2048 + s0 + tx] = f2bf(tile[tx][i]);
}

// ---------------- flash attention: 1 block = (head, 64 q rows), 4 waves x 16 rows ----------------
__global__ __launch_bounds__(256, 2)
void attn_k(const u16* __restrict__ qr, const u16* __restrict__ kr,
            const u16* __restrict__ vt, u16* __restrict__ aout) {
  __shared__ __align__(16) u16 plds[4][16 * 40];  // wave-private P tile, stride 40 (16B-aligned reads)
  const int bh = blockIdx.x;
  const int qb = (int)blockIdx.y << 6;
  const int tid = threadIdx.x;
  const int w = tid >> 6, l = tid & 63, lg = l >> 4, ll = l & 15;
  const u16* Q  = qr + (size_t)bh * (2048 * 64);
  const u16* Kp = kr + (size_t)bh * (2048 * 64);
  const u16* Vp = vt + (size_t)bh * (64 * 2048);
  const int q0 = qb + w * 16;
  // Q fragments: A[row=lane&15][k=8*(lane>>4)+i]
  const bf16x8 qf0 = *(const bf16x8*)&Q[(q0 + ll) * 64 + lg * 8];
  const bf16x8 qf1 = *(const bf16x8*)&Q[(q0 + ll) * 64 + 32 + lg * 8];
  f32x4 o[4] = {};
  float mrow[4] = {-1e30f, -1e30f, -1e30f, -1e30f};
  float lrow[4] = {0.f, 0.f, 0.f, 0.f};
  u16* myp = plds[w];
  const int nch = ((q0 + 15) >> 5) + 1;  // KV chunks of 32, causal bound per wave
  for (int ch = 0; ch < nch; ++ch) {
    const int kb = ch << 5;
    f32x4 s0 = {}, s1 = {};
    {
      const u16* k0 = &Kp[(kb + ll) * 64 + lg * 8];
      s0 = mfma16(qf0, *(const bf16x8*)k0, s0);
      s0 = mfma16(qf1, *(const bf16x8*)(k0 + 32), s0);
      const u16* k1 = k0 + 16 * 64;
      s1 = mfma16(qf0, *(const bf16x8*)k1, s1);
      s1 = mfma16(qf1, *(const bf16x8*)(k1 + 32), s1);
    }
    if (kb + 31 > q0) {  // causal mask (only near diagonal)
#pragma unroll
      for (int r = 0; r < 4; ++r) {
        const int qg = q0 + lg * 4 + r;
        if (kb + ll > qg) s0[r] = -1e30f;
        if (kb + 16 + ll > qg) s1[r] = -1e30f;
      }
    }
    float cm[4];
#pragma unroll
    for (int r = 0; r < 4; ++r) cm[r] = fmaxf(s0[r], s1[r]);
#pragma unroll
    for (int d = 1; d < 16; d <<= 1)
#pragma unroll
      for (int r = 0; r < 4; ++r) cm[r] = fmaxf(cm[r], __shfl_xor(cm[r], d));
    float psum[4];
#pragma unroll
    for (int r = 0; r < 4; ++r) {
      const float mn = fmaxf(mrow[r], cm[r]);
      const float esc = __expf(mrow[r] - mn);
      mrow[r] = mn;
      lrow[r] *= esc;
      o[0][r] *= esc; o[1][r] *= esc; o[2][r] *= esc; o[3][r] *= esc;
      const float p0 = __expf(s0[r] - mn);
      const float p1 = __expf(s1[r] - mn);
      psum[r] = p0 + p1;
      myp[(lg * 4 + r) * 40 + ll]      = f2bf(p0);
      myp[(lg * 4 + r) * 40 + 16 + ll] = f2bf(p1);
    }
#pragma unroll
    for (int d = 1; d < 16; d <<= 1)
#pragma unroll
      for (int r = 0; r < 4; ++r) psum[r] += __shfl_xor(psum[r], d);
#pragma unroll
    for (int r = 0; r < 4; ++r) lrow[r] += psum[r];
    asm volatile("s_waitcnt lgkmcnt(0)" ::: "memory");
    // P back as A-frag; V as B-frag from transposed vt (contiguous 16B per lane)
    const bf16x8 pa = *(const bf16x8*)&myp[ll * 40 + lg * 8];
#pragma unroll
    for (int v = 0; v < 4; ++v) {
      const bf16x8 vf = *(const bf16x8*)&Vp[(size_t)(v * 16 + ll) * 2048 + kb + lg * 8];
      o[v] = mfma16(pa, vf, o[v]);
    }
  }
  const int hcol = (bh & 15) << 6;
  const int tokb = ((bh >> 4) << 11) + q0 + lg * 4;
#pragma unroll
  for (int r = 0; r < 4; ++r) {
    const float inv = 1.0f / lrow[r];
    u16* orow = aout + (size_t)(tokb + r) * 1024 + hcol;
#pragma unroll
    for (int v = 0; v < 4; ++v)
      orow[v * 16 + ll] = f2bf(o[v][r] * inv);
  }
}

extern "C" void kernel_launch(void* const* d_in, const int* in_sizes, int n_in,
                              void* d_out, int out_size, void* d_ws, size_t ws_size,
                              hipStream_t stream) {
  const float* x    = (const float*)d_in[0];
  // d_in[1] = mask (tril) — causality implemented directly
  const float* fc   = (const float*)d_in[2];
  const float* fs   = (const float*)d_in[3];
  const float* Wqkv = (const float*)d_in[4];
  const float* bqkv = (const float*)d_in[5];
  const float* Wo   = (const float*)d_in[6];
  const float* bo   = (const float*)d_in[7];
  float* out = (float*)d_out;

  size_t off = 0;
  auto alloc = [&](size_t bytes) {
    void* p = (char*)d_ws + off;
    off += (bytes + 255) & ~(size_t)255;
    return p;
  };
  u16*   xb   = (u16*)  alloc(4096ull * 1024 * 2);   // x bf16
  u16*   wqt  = (u16*)  alloc(3072ull * 1024 * 2);   // W_qkv^T bf16
  u16*   wot  = (u16*)  alloc(1024ull * 1024 * 2);   // W_o^T bf16
  float* qkvf = (float*)alloc(4096ull * 3072 * 4);   // qkv fp32
  u16*   qr_  = (u16*)  alloc(32ull * 2048 * 64 * 2);// q roped, head-major
  u16*   kr_  = (u16*)  alloc(32ull * 2048 * 64 * 2);// k roped, head-major
  u16*   vt_  = (u16*)  alloc(32ull * 64 * 2048 * 2);// v transposed [bh][d][s]
  u16*   ao_  = (u16*)  alloc(4096ull * 1024 * 2);   // attention out bf16, token-major

  cast_bf16_kernel<<<2048, 256, 0, stream>>>(x, xb, 4096 * 1024);
  transpose_cast_k<<<dim3(48, 16), 256, 0, stream>>>(Wqkv, wqt, 1024, 3072);
  transpose_cast_k<<<dim3(16, 16), 256, 0, stream>>>(Wo, wot, 1024, 1024);
  gemm_bt<<<dim3(32 * 24), 256, 0, stream>>>(xb, wqt, bqkv, qkvf, 4096, 3072, 1024);
  rope_split_k<<<dim3(4096), 512, 0, stream>>>(qkvf, fc, fs, qr_, kr_);
  v_transpose_k<<<dim3(32, 32), 256, 0, stream>>>(qkvf, vt_);
  attn_k<<<dim3(32, 32), 256, 0, stream>>>(qr_, kr_, vt_, ao_);
  gemm_bt<<<dim3(32 * 8), 256, 0, stream>>>(ao_, wot, bo, out, 4096, 1024, 1024);
}